// Round 1
// baseline (440.674 us; speedup 1.0000x reference)
//
#include <hip/hip_runtime.h>
#include <cstdint>
#include <cstddef>

using short8 = __attribute__((ext_vector_type(8))) short;
using f32x4  = __attribute__((ext_vector_type(4))) float;

#define AS_G __attribute__((address_space(1)))
#define AS_L __attribute__((address_space(3)))

static __device__ __forceinline__ void ld_lds16(const void* g, void* l) {
  __builtin_amdgcn_global_load_lds((const AS_G void*)g, (AS_L void*)l, 16, 0, 0);
}
static __device__ __forceinline__ void ld_lds4(const void* g, void* l) {
  __builtin_amdgcn_global_load_lds((const AS_G void*)g, (AS_L void*)l, 4, 0, 0);
}

static __device__ __forceinline__ unsigned short f2bf(float f) {
  unsigned int u = __float_as_uint(f);
  u = u + 0x7fffu + ((u >> 16) & 1u);   // RNE
  return (unsigned short)(u >> 16);
}

// ---------------------------------------------------------------------------
// prep: f32 -> bf16 converts (u, W_A, and W_B|W_d stacked [128][512])
// ---------------------------------------------------------------------------
__global__ __launch_bounds__(256) void prep_kernel(
    const float* __restrict__ u, const float* __restrict__ WA,
    const float* __restrict__ WB, const float* __restrict__ Wd,
    unsigned short* __restrict__ ub, unsigned short* __restrict__ WAb,
    unsigned short* __restrict__ Wbd)
{
  const int NU = 8388608 / 4;       // u float4 count
  const int NA = 2097152 / 4;       // W_A
  const int NB = 32768 / 4;         // W_B
  const int ND = 32768 / 4;         // W_d
  const int total = NU + NA + NB + ND;
  for (int i = blockIdx.x * blockDim.x + threadIdx.x; i < total;
       i += gridDim.x * blockDim.x) {
    const float4* s4; ushort4* d4; int j;
    if (i < NU)                { s4 = (const float4*)u;  d4 = (ushort4*)ub;   j = i; }
    else if (i < NU + NA)      { s4 = (const float4*)WA; d4 = (ushort4*)WAb;  j = i - NU; }
    else if (i < NU + NA + NB) { s4 = (const float4*)WB; d4 = (ushort4*)Wbd;  j = i - NU - NA; }
    else                       { s4 = (const float4*)Wd; d4 = (ushort4*)Wbd + NB; j = i - NU - NA - NB; }
    float4 v = s4[j];
    ushort4 o;
    o.x = f2bf(v.x); o.y = f2bf(v.y); o.z = f2bf(v.z); o.w = f2bf(v.w);
    d4[j] = o;
  }
}

// ---------------------------------------------------------------------------
// GEMM: C[m,n] = sum_k U[m,k]*W[n,k], bf16 MFMA 16x16x32, 128x128 tile, BK=32
// EPI=1: A epilogue: tanh(x+bias)*0.125, zero diagonal cols, store bf16 [M][4096]
// EPI=2: Bu/d epilogue: col<64 -> Bu=x+bB (f32); col>=64 -> d=sigmoid(x+bd) (f32)
// ---------------------------------------------------------------------------
template <int EPI>
__global__ __launch_bounds__(256) void gemm_kernel(
    const unsigned short* __restrict__ U,   // [M][512] bf16
    const unsigned short* __restrict__ W,   // [N][512] bf16
    const float* __restrict__ bias0,
    const float* __restrict__ bias1,
    unsigned short* __restrict__ outA,      // EPI=1
    float* __restrict__ outBu,              // EPI=2
    float* __restrict__ outd)               // EPI=2
{
  __shared__ unsigned short lA[128 * 32];   // 8 KB, row-major [128][32]
  __shared__ unsigned short lB[128 * 32];

  const int tid  = threadIdx.x;
  const int lane = tid & 63;
  const int wv   = tid >> 6;
  const int wuni = __builtin_amdgcn_readfirstlane(wv);
  const int bm = blockIdx.x * 128;
  const int bn = blockIdx.y * 128;

  f32x4 acc[4][4] = {};

  const int srow = tid >> 2;        // staging row 0..63 (c>>2)
  const int sc   = tid & 3;         // 16B chunk within row

  for (int k0 = 0; k0 < 512; k0 += 32) {
    const unsigned short* gA0 = U + (size_t)(bm + srow) * 512 + k0 + sc * 8;
    const unsigned short* gB0 = W + (size_t)(bn + srow) * 512 + k0 + sc * 8;
    unsigned short* lA0 = lA + wuni * 512;           // wave base (1024 B)
    unsigned short* lB0 = lB + wuni * 512;
    ld_lds16(gA0,             lA0);
    ld_lds16(gA0 + 64 * 512,  lA0 + 2048);           // rows 64..127
    ld_lds16(gB0,             lB0);
    ld_lds16(gB0 + 64 * 512,  lB0 + 2048);
    __syncthreads();                                  // drains vmcnt(0)

    const int r16 = lane & 15, kq = lane >> 4;
    const int wm = (wv >> 1) * 64, wn = (wv & 1) * 64;
    short8 af[4], bfr[4];
#pragma unroll
    for (int f = 0; f < 4; ++f) {
      af[f]  = *(const short8*)&lA[(wm + f * 16 + r16) * 32 + kq * 8];
      bfr[f] = *(const short8*)&lB[(wn + f * 16 + r16) * 32 + kq * 8];
    }
#pragma unroll
    for (int i = 0; i < 4; ++i)
#pragma unroll
      for (int j = 0; j < 4; ++j)
        acc[i][j] = __builtin_amdgcn_mfma_f32_16x16x32_bf16(af[i], bfr[j], acc[i][j], 0, 0, 0);
    __syncthreads();
  }

  // epilogue (C/D layout: col = lane&15, row = (lane>>4)*4 + reg)
  const int r16 = lane & 15, kq = lane >> 4;
  const int wm = (wv >> 1) * 64, wn = (wv & 1) * 64;
#pragma unroll
  for (int j = 0; j < 4; ++j) {
    const int col = bn + wn + j * 16 + r16;
    if (EPI == 1) {
      const float bias = bias0[col];
      const bool diag = ((col & 63) == (col >> 6));
#pragma unroll
      for (int i = 0; i < 4; ++i) {
        const int row = bm + wm + i * 16 + kq * 4;
#pragma unroll
        for (int q = 0; q < 4; ++q) {
          float z = acc[i][j][q] + bias;
          float ax = fabsf(z);
          float e = __expf(-2.f * ax);
          float t = (1.f - e) / (1.f + e);            // tanh(|z|)
          t = copysignf(t, z);
          float v = diag ? 0.f : 0.125f * t;          // *1/sqrt(64), diag zeroed
          outA[(size_t)(row + q) * 4096 + col] = f2bf(v);
        }
      }
    } else {
      const bool isBu = (col < 64);
      const float bias = isBu ? bias0[col] : bias1[col - 64];
#pragma unroll
      for (int i = 0; i < 4; ++i) {
        const int row = bm + wm + i * 16 + kq * 4;
#pragma unroll
        for (int q = 0; q < 4; ++q) {
          float z = acc[i][j][q] + bias;
          if (isBu) outBu[(size_t)(row + q) * 64 + col] = z;
          else      outd [(size_t)(row + q) * 64 + (col - 64)] = 1.f / (1.f + __expf(-z));
        }
      }
    }
  }
}

// ---------------------------------------------------------------------------
// scan: h_t = A_t h_{t-1} + d_t*h + Bu_t. Burn-in chunked: each block owns
// 64 payload steps, recomputes from h=0 starting R_BURN=96 steps earlier
// (contraction ~0.925/step => residual ~5e-4 in h). Single wave per block;
// triple-buffered A tile via global_load_lds; XOR-swizzled A rows (source-
// side swizzle, linear LDS dest); counted vmcnt (never 0 in loop).
// ---------------------------------------------------------------------------
#define R_BURN 96
__global__ __launch_bounds__(64) void scan_kernel(
    const unsigned short* __restrict__ Ag,  // [B*T][4096] bf16, diag=0
    const float* __restrict__ Bu,           // [B*T][64]
    const float* __restrict__ dg,           // [B*T][64]
    float* __restrict__ hout,               // [B*T][64]
    float* __restrict__ dump)               // [256][64] burn-in dummy sink
{
  __shared__ uint4 Ab[3][512];              // 3 x 8 KB
  __shared__ float Bu3[3][64];
  __shared__ float d3[3][64];
  __shared__ float hb[2][64];

  const int lane = threadIdx.x;
  const int b = blockIdx.y, ci = blockIdx.x;
  const int t0 = ci * 64, tend = t0 + 64;
  const int tstart = (t0 >= R_BURN) ? (t0 - R_BURN) : 0;
  const size_t base = (size_t)b * 2048;

  hb[0][lane] = 0.f;

  const int irow = lane >> 3;                 // row within 8-row group
  const int scc  = (lane & 7) ^ irow;         // pre-swizzled source chunk

  auto stage = [&](int slot, int t) {
    const size_t m = base + t;
    const unsigned short* arow = Ag + m * 4096;
#pragma unroll
    for (int s = 0; s < 8; ++s)               // 8 x 1KB: rows 8s..8s+7
      ld_lds16(arow + (s * 8 + irow) * 64 + scc * 8, &Ab[slot][s * 64]);
    ld_lds4(Bu + m * 64 + lane, &Bu3[slot][0]);
    ld_lds4(dg + m * 64 + lane, &d3[slot][0]);
  };

  stage(0, tstart);
  stage(1, tstart + 1);
  float* dmp = dump + (size_t)(b * 32 + ci) * 64;

  int k = 0;
  for (int t = tstart; t < tend; ++t, ++k) {
    const int slot = k % 3;
    stage((k + 2) % 3, (t + 2 < tend) ? (t + 2) : (tend - 1));  // clamped: uniform count
    if (k == 0) { asm volatile("s_waitcnt vmcnt(20)" ::: "memory"); }
    else        { asm volatile("s_waitcnt vmcnt(21)" ::: "memory"); }
    asm volatile("s_waitcnt lgkmcnt(0)" ::: "memory");
    __builtin_amdgcn_sched_barrier(0);

    const int p = k & 1;
    float a0 = Bu3[slot][lane], a1 = 0.f, a2 = 0.f, a3 = 0.f;
#pragma unroll
    for (int c8 = 0; c8 < 8; ++c8) {
      uint4 av = Ab[slot][lane * 8 + (c8 ^ (lane & 7))];  // swizzled read back
      const float4* hp = (const float4*)&hb[p][c8 * 8];
      float4 h0 = hp[0], h1 = hp[1];
      a0 = fmaf(__uint_as_float(av.x << 16),         h0.x, a0);
      a1 = fmaf(__uint_as_float(av.x & 0xffff0000u), h0.y, a1);
      a2 = fmaf(__uint_as_float(av.y << 16),         h0.z, a2);
      a3 = fmaf(__uint_as_float(av.y & 0xffff0000u), h0.w, a3);
      a0 = fmaf(__uint_as_float(av.z << 16),         h1.x, a0);
      a1 = fmaf(__uint_as_float(av.z & 0xffff0000u), h1.y, a1);
      a2 = fmaf(__uint_as_float(av.w << 16),         h1.z, a2);
      a3 = fmaf(__uint_as_float(av.w & 0xffff0000u), h1.w, a3);
    }
    float acc = (a0 + a1) + (a2 + a3);
    acc += d3[slot][lane] * hb[p][lane];      // fp32 diagonal
    hb[p ^ 1][lane] = acc;
    float* dst = (t >= t0) ? (hout + (base + t) * 64) : dmp;
    dst[lane] = acc;
  }
  asm volatile("s_waitcnt vmcnt(0) lgkmcnt(0)" ::: "memory");
}

// ---------------------------------------------------------------------------
// out[m,c] = sum_k h[m,k]*Cw[c,k] + D[c]*u[m,c]
// block: 64 m-rows x 128 cols; C staged in LDS with +1 pad; h via L1 broadcast
// ---------------------------------------------------------------------------
__global__ __launch_bounds__(256) void out_kernel(
    const float* __restrict__ h, const float* __restrict__ Cw,
    const float* __restrict__ Dv, const float* __restrict__ u,
    float* __restrict__ out)
{
  __shared__ float Cs[128][65];
  const int tid = threadIdx.x;
  const int m0 = blockIdx.x * 64;
  const int c0 = blockIdx.y * 128;

  {
    const float4* src = (const float4*)(Cw + (size_t)c0 * 64);
#pragma unroll
    for (int r = 0; r < 8; ++r) {
      int f = tid + r * 256;                  // 0..2047 float4s
      float4 v = src[f];
      int row = f >> 4, c4 = (f & 15) << 2;
      Cs[row][c4] = v.x; Cs[row][c4 + 1] = v.y; Cs[row][c4 + 2] = v.z; Cs[row][c4 + 3] = v.w;
    }
  }
  __syncthreads();

  const int ci = tid & 127, mg = tid >> 7;
  const int mbase = m0 + mg * 32;
  const float Dc = Dv[c0 + ci];
  float accs[32];
#pragma unroll
  for (int i = 0; i < 32; ++i) accs[i] = 0.f;

  for (int k4 = 0; k4 < 16; ++k4) {
    float c0v = Cs[ci][k4 * 4], c1v = Cs[ci][k4 * 4 + 1];
    float c2v = Cs[ci][k4 * 4 + 2], c3v = Cs[ci][k4 * 4 + 3];
#pragma unroll
    for (int mi = 0; mi < 32; ++mi) {
      float4 hv = *(const float4*)(h + (size_t)(mbase + mi) * 64 + k4 * 4);
      accs[mi] = fmaf(hv.x, c0v, fmaf(hv.y, c1v, fmaf(hv.z, c2v, fmaf(hv.w, c3v, accs[mi]))));
    }
  }
#pragma unroll
  for (int mi = 0; mi < 32; ++mi) {
    size_t row = (size_t)(mbase + mi);
    float uu = u[row * 512 + c0 + ci];
    out[row * 512 + c0 + ci] = accs[mi] + Dc * uu;
  }
}

// ---------------------------------------------------------------------------
extern "C" void kernel_launch(void* const* d_in, const int* in_sizes, int n_in,
                              void* d_out, int out_size, void* d_ws, size_t ws_size,
                              hipStream_t stream) {
  (void)in_sizes; (void)n_in; (void)out_size; (void)ws_size;
  const float* u   = (const float*)d_in[0];
  const float* Wdw = (const float*)d_in[1];
  const float* Wdb = (const float*)d_in[2];
  const float* WAw = (const float*)d_in[3];
  const float* WAb = (const float*)d_in[4];
  const float* WBw = (const float*)d_in[5];
  const float* WBb = (const float*)d_in[6];
  const float* Cw  = (const float*)d_in[7];
  const float* Dv  = (const float*)d_in[8];
  float* out = (float*)d_out;

  char* ws = (char*)d_ws;
  unsigned short* ub    = (unsigned short*)ws; ws += 16777216ull;   // u bf16 [16384][512]
  unsigned short* WAb16 = (unsigned short*)ws; ws += 4194304ull;    // W_A bf16 [4096][512]
  unsigned short* Wbd   = (unsigned short*)ws; ws += 131072ull;     // W_B|W_d bf16 [128][512]
  unsigned short* Aoff  = (unsigned short*)ws; ws += 134217728ull;  // A bf16 [16384][4096], diag=0
  float* BuA  = (float*)ws; ws += 4194304ull;                       // Bu f32 [16384][64]
  float* dA   = (float*)ws; ws += 4194304ull;                       // d  f32 [16384][64]
  float* hA   = (float*)ws; ws += 4194304ull;                       // h  f32 [16384][64]
  float* dump = (float*)ws; ws += 65536ull;                         // burn-in sink

  prep_kernel<<<2048, 256, 0, stream>>>(u, WAw, WBw, Wdw, ub, WAb16, Wbd);
  gemm_kernel<1><<<dim3(128, 32), 256, 0, stream>>>(ub, WAb16, WAb, nullptr, Aoff, nullptr, nullptr);
  gemm_kernel<2><<<dim3(128, 1), 256, 0, stream>>>(ub, Wbd, WBb, Wdb, nullptr, BuA, dA);
  scan_kernel<<<dim3(32, 8), 64, 0, stream>>>(Aoff, BuA, dA, hA, dump);
  out_kernel<<<dim3(256, 4), 256, 0, stream>>>(hA, Cw, Dv, u, out);
}

// Round 3
// 422.110 us; speedup vs baseline: 1.0440x; 1.0440x over previous
//
#include <hip/hip_runtime.h>
#include <cstdint>
#include <cstddef>

using short8 = __attribute__((ext_vector_type(8))) short;
using f32x4  = __attribute__((ext_vector_type(4))) float;

#define AS_G __attribute__((address_space(1)))
#define AS_L __attribute__((address_space(3)))

static __device__ __forceinline__ void ld_lds16(const void* g, void* l) {
  __builtin_amdgcn_global_load_lds((const AS_G void*)g, (AS_L void*)l, 16, 0, 0);
}
static __device__ __forceinline__ void ld_lds4(const void* g, void* l) {
  __builtin_amdgcn_global_load_lds((const AS_G void*)g, (AS_L void*)l, 4, 0, 0);
}

static __device__ __forceinline__ unsigned short f2bf(float f) {
  unsigned int u = __float_as_uint(f);
  u = u + 0x7fffu + ((u >> 16) & 1u);   // RNE
  return (unsigned short)(u >> 16);
}

// ---------------------------------------------------------------------------
// prep: f32 -> bf16 converts (u, W_A, and W_B|W_d stacked [128][512])
// ---------------------------------------------------------------------------
__global__ __launch_bounds__(256) void prep_kernel(
    const float* __restrict__ u, const float* __restrict__ WA,
    const float* __restrict__ WB, const float* __restrict__ Wd,
    unsigned short* __restrict__ ub, unsigned short* __restrict__ WAb,
    unsigned short* __restrict__ Wbd)
{
  const int NU = 8388608 / 4;
  const int NA = 2097152 / 4;
  const int NB = 32768 / 4;
  const int ND = 32768 / 4;
  const int total = NU + NA + NB + ND;
  for (int i = blockIdx.x * blockDim.x + threadIdx.x; i < total;
       i += gridDim.x * blockDim.x) {
    const float4* s4; ushort4* d4; int j;
    if (i < NU)                { s4 = (const float4*)u;  d4 = (ushort4*)ub;   j = i; }
    else if (i < NU + NA)      { s4 = (const float4*)WA; d4 = (ushort4*)WAb;  j = i - NU; }
    else if (i < NU + NA + NB) { s4 = (const float4*)WB; d4 = (ushort4*)Wbd;  j = i - NU - NA; }
    else                       { s4 = (const float4*)Wd; d4 = (ushort4*)Wbd + NB; j = i - NU - NA - NB; }
    float4 v = s4[j];
    ushort4 o;
    o.x = f2bf(v.x); o.y = f2bf(v.y); o.z = f2bf(v.z); o.w = f2bf(v.w);
    d4[j] = o;
  }
}

// ---------------------------------------------------------------------------
// GEMM: C[m,n] = sum_k U[m,k]*W[n,k], bf16 MFMA 16x16x32, 128x128 tile, BK=64.
// LDS tiles [128][64] bf16 with XOR chunk swizzle (chunk ^= row&7, 16B units).
// SWAPPED mfma operands: acc[i][j] = mfma(bfrag[j], afrag[i], acc) so each
// lane holds 4 CONSECUTIVE n at (m = lane&15, n0 = (lane>>4)*4) -> 8B packed
// epilogue stores.
// EPI=1: A = tanh(x+bias)*0.125, diag (n%64==n/64) zeroed, bf16 [M][4096]
// EPI=2: n<64 -> Bu = x+bB (f32); n>=64 -> d = sigmoid(x+bd) (f32)
// ---------------------------------------------------------------------------
template <int EPI>
__global__ __launch_bounds__(256) void gemm_kernel(
    const unsigned short* __restrict__ U,   // [M][512] bf16
    const unsigned short* __restrict__ W,   // [N][512] bf16
    const float* __restrict__ bias0,
    const float* __restrict__ bias1,
    unsigned short* __restrict__ outA,
    float* __restrict__ outBu,
    float* __restrict__ outd,
    int grid_m)                             // m-tiles (for swizzle decode)
{
  __shared__ unsigned short lA[128 * 64];   // 16 KB
  __shared__ unsigned short lB[128 * 64];   // 16 KB

  const int tid  = threadIdx.x;
  const int lane = tid & 63;
  const int wv   = tid >> 6;
  const int wuni = __builtin_amdgcn_readfirstlane(wv);

  // XCD swizzle: flat n-major (orig = bx*GN + by), 8 XCDs, nwg % 8 == 0
  int bx, by;
  {
    const int GN = gridDim.y;
    const int nwg = grid_m * GN;
    const int orig = blockIdx.x * GN + blockIdx.y;
    const int cpx = nwg >> 3;
    const int wg = (orig & 7) * cpx + (orig >> 3);
    bx = wg / GN; by = wg - bx * GN;
  }
  const int bm = bx * 128;
  const int bn = by * 128;

  f32x4 acc[4][4] = {};

  const int r16 = lane & 15, kq = lane >> 4;
  const int wm = (wv >> 1) * 64, wn = (wv & 1) * 64;

  for (int k0 = 0; k0 < 512; k0 += 64) {
#pragma unroll
    for (int l = 0; l < 4; ++l) {
      const int flat = l * 256 + tid;       // 16B-chunk index 0..1023
      const int row  = flat >> 3;
      const int cs   = (flat & 7) ^ (row & 7);
      const int ldsb = (l * 256 + wuni * 64) * 8;     // ushort units, wave-uniform
      ld_lds16(U + (size_t)(bm + row) * 512 + k0 + cs * 8, lA + ldsb);
      ld_lds16(W + (size_t)(bn + row) * 512 + k0 + cs * 8, lB + ldsb);
    }
    __syncthreads();                         // drains vmcnt(0)

#pragma unroll
    for (int kk = 0; kk < 2; ++kk) {
      short8 af[4], bfr[4];
#pragma unroll
      for (int f = 0; f < 4; ++f) {
        const int swz = ((kk * 4 + kq) ^ (r16 & 7)) * 8;
        af[f]  = *(const short8*)&lA[(wm + f * 16 + r16) * 64 + swz];
        bfr[f] = *(const short8*)&lB[(wn + f * 16 + r16) * 64 + swz];
      }
#pragma unroll
      for (int i = 0; i < 4; ++i)
#pragma unroll
        for (int j = 0; j < 4; ++j)
          acc[i][j] = __builtin_amdgcn_mfma_f32_16x16x32_bf16(bfr[j], af[i], acc[i][j], 0, 0, 0);
    }
    __syncthreads();
  }

  // epilogue: lane holds C[m][n0..n0+3], m = bm+wm+i*16+(lane&15),
  //           n0 = bn+wn+j*16+(lane>>4)*4
  const int mrow = lane & 15;
  const int ng   = (lane >> 4) * 4;
#pragma unroll
  for (int i = 0; i < 4; ++i) {
    const int m = bm + wm + i * 16 + mrow;
#pragma unroll
    for (int j = 0; j < 4; ++j) {
      const int nb = bn + wn + j * 16 + ng;
      if (EPI == 1) {
        float4 bi = *(const float4*)(bias0 + nb);
        const float* bp = (const float*)&bi;
        ushort4 o; unsigned short* op = (unsigned short*)&o;
#pragma unroll
        for (int q = 0; q < 4; ++q) {
          const int n = nb + q;
          float z = acc[i][j][q] + bp[q];
          float e = __expf(2.f * z);
          float t = 1.f - 2.f / (e + 1.f);
          float v = (((n & 63) == (n >> 6))) ? 0.f : 0.125f * t;
          op[q] = f2bf(v);
        }
        *(ushort4*)(outA + (size_t)m * 4096 + nb) = o;
      } else {
        const int n = wn + j * 16 + ng;      // bn == 0 for EPI=2
        if (n < 64) {
          float4 bi = *(const float4*)(bias0 + n);
          const float* bp = (const float*)&bi;
          float4 r; float* rp = (float*)&r;
#pragma unroll
          for (int q = 0; q < 4; ++q) rp[q] = acc[i][j][q] + bp[q];
          *(float4*)(outBu + (size_t)m * 64 + n) = r;
        } else {
          float4 bi = *(const float4*)(bias1 + (n - 64));
          const float* bp = (const float*)&bi;
          float4 r; float* rp = (float*)&r;
#pragma unroll
          for (int q = 0; q < 4; ++q) {
            float z = acc[i][j][q] + bp[q];
            rp[q] = 1.f / (1.f + __expf(-z));
          }
          *(float4*)(outd + (size_t)m * 64 + (n - 64)) = r;
        }
      }
    }
  }
}

// ---------------------------------------------------------------------------
// scan: h_t = A_t h_{t-1} + d_t*h_{t-1} + Bu_t. Chunked with burn-in R=64
// (per-step RMS contraction ~0.93 => residual ~1e-2 rel in h, ~2e-4 in out).
// 1 wave/block, 4-slot LDS pipeline, prefetch 3 tiles ahead (30 outstanding
// loads, counted vmcnt(30) - never drained to 0 in the loop). A rows are
// XOR-swizzled via pre-swizzled global source (linear LDS dest).
// ---------------------------------------------------------------------------
#define R_BURN 64
__global__ __launch_bounds__(64) void scan_kernel(
    const unsigned short* __restrict__ Ag,  // [B*T][4096] bf16, diag=0
    const float* __restrict__ Bu,           // [B*T][64]
    const float* __restrict__ dg,           // [B*T][64]
    float* __restrict__ hout)               // [B*T][64]
{
  __shared__ uint4 Ab[4][512];              // 4 x 8 KB
  __shared__ float Bu3[4][64];
  __shared__ float d3[4][64];
  __shared__ float hb[2][64];

  const int lane = threadIdx.x;
  const int b = blockIdx.y, ci = blockIdx.x;
  const int t0 = ci * 64, tend = t0 + 64;
  const int tstart = (t0 >= R_BURN) ? (t0 - R_BURN) : 0;
  const size_t base = (size_t)b * 2048;

  hb[0][lane] = 0.f;

  const int irow = lane >> 3;
  const int scc  = (lane & 7) ^ irow;

  auto stage = [&](int slot, int t) {
    const size_t m = base + t;
    const unsigned short* arow = Ag + m * 4096;
#pragma unroll
    for (int s = 0; s < 8; ++s)
      ld_lds16(arow + (s * 8 + irow) * 64 + scc * 8, &Ab[slot][s * 64]);
    ld_lds4(Bu + m * 64 + lane, &Bu3[slot][0]);
    ld_lds4(dg + m * 64 + lane, &d3[slot][0]);
  };

  stage(0, tstart);
  stage(1, tstart + 1 < tend ? tstart + 1 : tend - 1);
  stage(2, tstart + 2 < tend ? tstart + 2 : tend - 1);

  int k = 0;
  for (int t = tstart; t < tend; ++t, ++k) {
    const int slot = k & 3;
    stage((k + 3) & 3, (t + 3 < tend) ? (t + 3) : (tend - 1));
    asm volatile("s_waitcnt vmcnt(30)" ::: "memory");   // tile k drained
    asm volatile("s_waitcnt lgkmcnt(0)" ::: "memory");
    __builtin_amdgcn_sched_barrier(0);

    const int p = k & 1;
    float a0 = Bu3[slot][lane], a1 = 0.f, a2 = 0.f, a3 = 0.f;
#pragma unroll
    for (int c8 = 0; c8 < 8; ++c8) {
      uint4 av = Ab[slot][lane * 8 + (c8 ^ (lane & 7))];
      const float4* hp = (const float4*)&hb[p][c8 * 8];
      float4 h0 = hp[0], h1 = hp[1];
      a0 = fmaf(__uint_as_float(av.x << 16),         h0.x, a0);
      a1 = fmaf(__uint_as_float(av.x & 0xffff0000u), h0.y, a1);
      a2 = fmaf(__uint_as_float(av.y << 16),         h0.z, a2);
      a3 = fmaf(__uint_as_float(av.y & 0xffff0000u), h0.w, a3);
      a0 = fmaf(__uint_as_float(av.z << 16),         h1.x, a0);
      a1 = fmaf(__uint_as_float(av.z & 0xffff0000u), h1.y, a1);
      a2 = fmaf(__uint_as_float(av.w << 16),         h1.z, a2);
      a3 = fmaf(__uint_as_float(av.w & 0xffff0000u), h1.w, a3);
    }
    float acc = (a0 + a1) + (a2 + a3);
    acc += d3[slot][lane] * hb[p][lane];
    hb[p ^ 1][lane] = acc;
    if (t >= t0) hout[(base + t) * 64 + lane] = acc;
  }
  asm volatile("s_waitcnt vmcnt(0) lgkmcnt(0)" ::: "memory");
}

// ---------------------------------------------------------------------------
// out[m,c] = sum_k h[m,k]*Cw[c,k] + D[c]*u[m,c]
// block: 32 m-rows x 128 cols; C staged in LDS (+1 pad); h via L1 broadcast
// ---------------------------------------------------------------------------
__global__ __launch_bounds__(256) void out_kernel(
    const float* __restrict__ h, const float* __restrict__ Cw,
    const float* __restrict__ Dv, const float* __restrict__ u,
    float* __restrict__ out)
{
  __shared__ float Cs[128][65];
  const int tid = threadIdx.x;
  const int m0 = blockIdx.x * 32;
  const int c0 = blockIdx.y * 128;

  {
    const float4* src = (const float4*)(Cw + (size_t)c0 * 64);
#pragma unroll
    for (int r = 0; r < 8; ++r) {
      int f = tid + r * 256;
      float4 v = src[f];
      int row = f >> 4, c4 = (f & 15) << 2;
      Cs[row][c4] = v.x; Cs[row][c4 + 1] = v.y; Cs[row][c4 + 2] = v.z; Cs[row][c4 + 3] = v.w;
    }
  }
  __syncthreads();

  const int ci = tid & 127, mg = tid >> 7;
  const int mbase = m0 + mg * 16;
  const float Dc = Dv[c0 + ci];
  float accs[16];
#pragma unroll
  for (int i = 0; i < 16; ++i) accs[i] = 0.f;

  for (int k4 = 0; k4 < 16; ++k4) {
    float c0v = Cs[ci][k4 * 4], c1v = Cs[ci][k4 * 4 + 1];
    float c2v = Cs[ci][k4 * 4 + 2], c3v = Cs[ci][k4 * 4 + 3];
#pragma unroll
    for (int mi = 0; mi < 16; ++mi) {
      float4 hv = *(const float4*)(h + (size_t)(mbase + mi) * 64 + k4 * 4);
      accs[mi] = fmaf(hv.x, c0v, fmaf(hv.y, c1v, fmaf(hv.z, c2v, fmaf(hv.w, c3v, accs[mi]))));
    }
  }
#pragma unroll
  for (int mi = 0; mi < 16; ++mi) {
    size_t row = (size_t)(mbase + mi);
    float uu = u[row * 512 + c0 + ci];
    out[row * 512 + c0 + ci] = accs[mi] + Dc * uu;
  }
}

// ---------------------------------------------------------------------------
extern "C" void kernel_launch(void* const* d_in, const int* in_sizes, int n_in,
                              void* d_out, int out_size, void* d_ws, size_t ws_size,
                              hipStream_t stream) {
  (void)in_sizes; (void)n_in; (void)out_size; (void)ws_size;
  const float* u   = (const float*)d_in[0];
  const float* Wdw = (const float*)d_in[1];
  const float* Wdb = (const float*)d_in[2];
  const float* WAw = (const float*)d_in[3];
  const float* WAb = (const float*)d_in[4];
  const float* WBw = (const float*)d_in[5];
  const float* WBb = (const float*)d_in[6];
  const float* Cw  = (const float*)d_in[7];
  const float* Dv  = (const float*)d_in[8];
  float* out = (float*)d_out;

  char* ws = (char*)d_ws;
  unsigned short* ub    = (unsigned short*)ws; ws += 16777216ull;   // u bf16
  unsigned short* WAb16 = (unsigned short*)ws; ws += 4194304ull;    // W_A bf16
  unsigned short* Wbd   = (unsigned short*)ws; ws += 131072ull;     // W_B|W_d bf16
  unsigned short* Aoff  = (unsigned short*)ws; ws += 134217728ull;  // A bf16, diag=0
  float* BuA  = (float*)ws; ws += 4194304ull;
  float* dA   = (float*)ws; ws += 4194304ull;
  float* hA   = (float*)ws; ws += 4194304ull;

  prep_kernel<<<2048, 256, 0, stream>>>(u, WAw, WBw, Wdw, ub, WAb16, Wbd);
  gemm_kernel<1><<<dim3(128, 32), 256, 0, stream>>>(ub, WAb16, WAb, nullptr, Aoff, nullptr, nullptr, 128);
  gemm_kernel<2><<<dim3(128, 1), 256, 0, stream>>>(ub, Wbd, WBb, Wdb, nullptr, BuA, dA, 128);
  scan_kernel<<<dim3(32, 8), 64, 0, stream>>>(Aoff, BuA, dA, hA);
  out_kernel<<<dim3(512, 4), 256, 0, stream>>>(hA, Cw, Dv, u, out);
}

// Round 5
// 403.277 us; speedup vs baseline: 1.0927x; 1.0467x over previous
//
#include <hip/hip_runtime.h>
#include <cstdint>
#include <cstddef>

using short8 = __attribute__((ext_vector_type(8))) short;
using f32x4  = __attribute__((ext_vector_type(4))) float;

#define AS_G __attribute__((address_space(1)))
#define AS_L __attribute__((address_space(3)))

static __device__ __forceinline__ void ld_lds16(const void* g, void* l) {
  __builtin_amdgcn_global_load_lds((const AS_G void*)g, (AS_L void*)l, 16, 0, 0);
}

static __device__ __forceinline__ unsigned short f2bf(float f) {
  unsigned int u = __float_as_uint(f);
  u = u + 0x7fffu + ((u >> 16) & 1u);   // RNE
  return (unsigned short)(u >> 16);
}

// ---------------------------------------------------------------------------
// prep: f32 -> bf16 converts. W_A rows are PERMUTED by sigma(n') = (n'&63)*64
// + (n'>>6) so the GEMM emits A-transpose (A'[t][c*64+r] = A_t[r][c]) with
// packed stores. Also emits the sigma-permuted f32 bias copy.
// ---------------------------------------------------------------------------
__global__ __launch_bounds__(256) void prep_kernel(
    const float* __restrict__ u, const float* __restrict__ WA,
    const float* __restrict__ WB, const float* __restrict__ Wd,
    const float* __restrict__ WAbias,
    unsigned short* __restrict__ ub, unsigned short* __restrict__ WAb,
    unsigned short* __restrict__ Wbd, float* __restrict__ biasP)
{
  const int gtid = blockIdx.x * blockDim.x + threadIdx.x;
  if (gtid < 4096) biasP[gtid] = WAbias[(gtid & 63) * 64 + (gtid >> 6)];

  const int NU = 8388608 / 4;
  const int NA = 2097152 / 4;
  const int NB = 32768 / 4;
  const int ND = 32768 / 4;
  const int total = NU + NA + NB + ND;
  for (int i = gtid; i < total; i += gridDim.x * blockDim.x) {
    const float4* s4; ushort4* d4; int j, sj;
    if (i < NU)                { s4 = (const float4*)u;  d4 = (ushort4*)ub;  j = i; sj = j; }
    else if (i < NU + NA)      { s4 = (const float4*)WA; d4 = (ushort4*)WAb; j = i - NU;
                                 const int row = j >> 7, c4 = j & 127;
                                 sj = ((row & 63) * 64 + (row >> 6)) * 128 + c4; }
    else if (i < NU + NA + NB) { s4 = (const float4*)WB; d4 = (ushort4*)Wbd; j = i - NU - NA; sj = j; }
    else                       { s4 = (const float4*)Wd; d4 = (ushort4*)Wbd + NB; j = i - NU - NA - NB; sj = j; }
    float4 v = s4[sj];
    ushort4 o;
    o.x = f2bf(v.x); o.y = f2bf(v.y); o.z = f2bf(v.z); o.w = f2bf(v.w);
    d4[j] = o;
  }
}

// ---------------------------------------------------------------------------
// GEMM: C[m,n] = sum_k U[m,k]*W[n,k], bf16 MFMA 16x16x32, 128x128 tile, BK=64.
// LDS XOR chunk swizzle; swapped mfma operands -> lane holds 4 consecutive n.
// EPI=1: A' = tanh(x+biasP)*0.125, diag zeroed, bf16, NONTEMPORAL stores.
// EPI=2: n<64 -> Bu = x+bB (f32); n>=64 -> d = sigmoid(x+bd) (f32)
// ---------------------------------------------------------------------------
template <int EPI>
__global__ __launch_bounds__(256) void gemm_kernel(
    const unsigned short* __restrict__ U,   // [M][512] bf16
    const unsigned short* __restrict__ W,   // [N][512] bf16
    const float* __restrict__ bias0,
    const float* __restrict__ bias1,
    unsigned short* __restrict__ outA,
    float* __restrict__ outBu,
    float* __restrict__ outd,
    int grid_m)
{
  __shared__ unsigned short lA[128 * 64];   // 16 KB
  __shared__ unsigned short lB[128 * 64];   // 16 KB

  const int tid  = threadIdx.x;
  const int lane = tid & 63;
  const int wv   = tid >> 6;
  const int wuni = __builtin_amdgcn_readfirstlane(wv);

  int bx, by;
  {
    const int GN = gridDim.y;
    const int nwg = grid_m * GN;
    const int orig = blockIdx.x * GN + blockIdx.y;
    const int cpx = nwg >> 3;
    const int wg = (orig & 7) * cpx + (orig >> 3);
    bx = wg / GN; by = wg - bx * GN;
  }
  const int bm = bx * 128;
  const int bn = by * 128;

  f32x4 acc[4][4] = {};

  const int r16 = lane & 15, kq = lane >> 4;
  const int wm = (wv >> 1) * 64, wn = (wv & 1) * 64;

  for (int k0 = 0; k0 < 512; k0 += 64) {
#pragma unroll
    for (int l = 0; l < 4; ++l) {
      const int flat = l * 256 + tid;
      const int row  = flat >> 3;
      const int cs   = (flat & 7) ^ (row & 7);
      const int ldsb = (l * 256 + wuni * 64) * 8;
      ld_lds16(U + (size_t)(bm + row) * 512 + k0 + cs * 8, lA + ldsb);
      ld_lds16(W + (size_t)(bn + row) * 512 + k0 + cs * 8, lB + ldsb);
    }
    __syncthreads();

#pragma unroll
    for (int kk = 0; kk < 2; ++kk) {
      short8 af[4], bfr[4];
#pragma unroll
      for (int f = 0; f < 4; ++f) {
        const int swz = ((kk * 4 + kq) ^ (r16 & 7)) * 8;
        af[f]  = *(const short8*)&lA[(wm + f * 16 + r16) * 64 + swz];
        bfr[f] = *(const short8*)&lB[(wn + f * 16 + r16) * 64 + swz];
      }
#pragma unroll
      for (int i = 0; i < 4; ++i)
#pragma unroll
        for (int j = 0; j < 4; ++j)
          acc[i][j] = __builtin_amdgcn_mfma_f32_16x16x32_bf16(bfr[j], af[i], acc[i][j], 0, 0, 0);
    }
    __syncthreads();
  }

  const int mrow = lane & 15;
  const int ng   = (lane >> 4) * 4;
#pragma unroll
  for (int i = 0; i < 4; ++i) {
    const int m = bm + wm + i * 16 + mrow;
#pragma unroll
    for (int j = 0; j < 4; ++j) {
      const int nb = bn + wn + j * 16 + ng;
      if (EPI == 1) {
        float4 bi = *(const float4*)(bias0 + nb);
        const float* bp = (const float*)&bi;
        unsigned long long o = 0;
#pragma unroll
        for (int q = 0; q < 4; ++q) {
          const int n = nb + q;
          float z = acc[i][j][q] + bp[q];
          float e = __expf(2.f * z);
          float t = 1.f - 2.f / (e + 1.f);
          float v = (((n & 63) == (n >> 6))) ? 0.f : 0.125f * t;
          o |= ((unsigned long long)f2bf(v)) << (q * 16);
        }
        __builtin_nontemporal_store(o, (unsigned long long*)(outA + (size_t)m * 4096 + nb));
      } else {
        const int n = wn + j * 16 + ng;
        if (n < 64) {
          float4 bi = *(const float4*)(bias0 + n);
          const float* bp = (const float*)&bi;
          float4 r; float* rp = (float*)&r;
#pragma unroll
          for (int q = 0; q < 4; ++q) rp[q] = acc[i][j][q] + bp[q];
          *(float4*)(outBu + (size_t)m * 64 + n) = r;
        } else {
          float4 bi = *(const float4*)(bias1 + (n - 64));
          const float* bp = (const float*)&bi;
          float4 r; float* rp = (float*)&r;
#pragma unroll
          for (int q = 0; q < 4; ++q) {
            float z = acc[i][j][q] + bp[q];
            rp[q] = 1.f / (1.f + __expf(-z));
          }
          *(float4*)(outd + (size_t)m * 64 + (n - 64)) = r;
        }
      }
    }
  }
}

// ---------------------------------------------------------------------------
// scan v3: h_t[r] = sum_c A_t[r][c] h[c] + d[r]h[r] + Bu[r].
// A' layout [t][c*64+r]. 4 waves/block: wave w owns c in [16w,16w+16).
// Lane r. Register-staged depth-4 pipeline (16 ushort loads/tile/wave,
// compiler-counted waits; raw s_barrier so prefetch stays in flight).
// h replicated in registers across waves (bitwise-identical update).
// Cross-wave reduce via double-buffered LDS partials, 1 barrier/iter.
// Burn-in 64 steps (contraction ~0.93 => ~9e-4 absmax, measured R3).
// ---------------------------------------------------------------------------
__global__ __launch_bounds__(256) void scan_kernel(
    const unsigned short* __restrict__ At,  // [B*T][4096] = A_t[r][c] at c*64+r
    const float* __restrict__ Bu,           // [B*T][64]
    const float* __restrict__ dg,           // [B*T][64]
    float* __restrict__ hout)               // [B*T][64]
{
  __shared__ float part[2][4][64];

  const int tid = threadIdx.x;
  const int r = tid & 63;
  const int w = tid >> 6;
  const int b = blockIdx.y, ci = blockIdx.x;
  const int t0 = ci * 64, tend = t0 + 64;
  const int tstart = (t0 >= 64) ? (t0 - 64) : 0;
  const size_t base = (size_t)b * 2048;

  float h = 0.f;

  unsigned short a0[16], a1[16], a2[16], a3[16];
  float bu0, bu1, bu2, bu3, dd0, dd1, dd2, dd3;

#define ISSUE(AV, BUV, DDV, T) do {                                          \
    const size_t _m = base + (size_t)(T);                                    \
    const unsigned short* _p = At + _m * 4096 + (w * 16) * 64 + r;           \
    _Pragma("unroll") for (int q = 0; q < 16; ++q) AV[q] = _p[q * 64];       \
    BUV = Bu[_m * 64 + r];                                                   \
    DDV = dg[_m * 64 + r];                                                   \
  } while (0)

#define COMPUTE(AV, BUV, DDV, PB, T) do {                                    \
    float _p0 = 0.f, _p1 = 0.f;                                              \
    _Pragma("unroll") for (int q = 0; q < 8; ++q) {                          \
      float _hv = __uint_as_float(                                           \
          __builtin_amdgcn_readlane(__float_as_uint(h), w * 16 + q));        \
      _p0 = fmaf(__uint_as_float(((unsigned)AV[q]) << 16), _hv, _p0);        \
    }                                                                        \
    _Pragma("unroll") for (int q = 8; q < 16; ++q) {                         \
      float _hv = __uint_as_float(                                           \
          __builtin_amdgcn_readlane(__float_as_uint(h), w * 16 + q));        \
      _p1 = fmaf(__uint_as_float(((unsigned)AV[q]) << 16), _hv, _p1);        \
    }                                                                        \
    part[PB][w][r] = _p0 + _p1;                                              \
    asm volatile("s_waitcnt lgkmcnt(0)" ::: "memory");                       \
    asm volatile("s_barrier" ::: "memory");                                  \
    float _hn = fmaf(DDV, h, BUV);                                           \
    _hn += part[PB][0][r]; _hn += part[PB][1][r];                            \
    _hn += part[PB][2][r]; _hn += part[PB][3][r];                            \
    h = _hn;                                                                 \
    if (w == 0 && (T) >= t0) hout[(base + (size_t)(T)) * 64 + r] = _hn;      \
  } while (0)

  int t = tstart;
  ISSUE(a0, bu0, dd0, t);
  ISSUE(a1, bu1, dd1, t + 1);
  ISSUE(a2, bu2, dd2, t + 2);

  const int ngroups = (tend - tstart) >> 2;
  for (int g = 0; g < ngroups; ++g) {
    { int tp = (t + 3 < tend) ? t + 3 : tend - 1; ISSUE(a3, bu3, dd3, tp); }
    COMPUTE(a0, bu0, dd0, 0, t);
    { int tp = (t + 4 < tend) ? t + 4 : tend - 1; ISSUE(a0, bu0, dd0, tp); }
    COMPUTE(a1, bu1, dd1, 1, t + 1);
    { int tp = (t + 5 < tend) ? t + 5 : tend - 1; ISSUE(a1, bu1, dd1, tp); }
    COMPUTE(a2, bu2, dd2, 0, t + 2);
    { int tp = (t + 6 < tend) ? t + 6 : tend - 1; ISSUE(a2, bu2, dd2, tp); }
    COMPUTE(a3, bu3, dd3, 1, t + 3);
    t += 4;
  }
#undef ISSUE
#undef COMPUTE
}

// ---------------------------------------------------------------------------
// out[m,c] = sum_k h[m,k]*Cw[c,k] + D[c]*u[m,c]
// ---------------------------------------------------------------------------
__global__ __launch_bounds__(256) void out_kernel(
    const float* __restrict__ h, const float* __restrict__ Cw,
    const float* __restrict__ Dv, const float* __restrict__ u,
    float* __restrict__ out)
{
  __shared__ float Cs[128][65];
  const int tid = threadIdx.x;
  const int m0 = blockIdx.x * 32;
  const int c0 = blockIdx.y * 128;

  {
    const float4* src = (const float4*)(Cw + (size_t)c0 * 64);
#pragma unroll
    for (int r = 0; r < 8; ++r) {
      int f = tid + r * 256;
      float4 v = src[f];
      int row = f >> 4, c4 = (f & 15) << 2;
      Cs[row][c4] = v.x; Cs[row][c4 + 1] = v.y; Cs[row][c4 + 2] = v.z; Cs[row][c4 + 3] = v.w;
    }
  }
  __syncthreads();

  const int ci = tid & 127, mg = tid >> 7;
  const int mbase = m0 + mg * 16;
  const float Dc = Dv[c0 + ci];
  float accs[16];
#pragma unroll
  for (int i = 0; i < 16; ++i) accs[i] = 0.f;

  for (int k4 = 0; k4 < 16; ++k4) {
    float c0v = Cs[ci][k4 * 4], c1v = Cs[ci][k4 * 4 + 1];
    float c2v = Cs[ci][k4 * 4 + 2], c3v = Cs[ci][k4 * 4 + 3];
#pragma unroll
    for (int mi = 0; mi < 16; ++mi) {
      float4 hv = *(const float4*)(h + (size_t)(mbase + mi) * 64 + k4 * 4);
      accs[mi] = fmaf(hv.x, c0v, fmaf(hv.y, c1v, fmaf(hv.z, c2v, fmaf(hv.w, c3v, accs[mi]))));
    }
  }
#pragma unroll
  for (int mi = 0; mi < 16; ++mi) {
    size_t row = (size_t)(mbase + mi);
    float uu = u[row * 512 + c0 + ci];
    out[row * 512 + c0 + ci] = accs[mi] + Dc * uu;
  }
}

// ---------------------------------------------------------------------------
extern "C" void kernel_launch(void* const* d_in, const int* in_sizes, int n_in,
                              void* d_out, int out_size, void* d_ws, size_t ws_size,
                              hipStream_t stream) {
  (void)in_sizes; (void)n_in; (void)out_size; (void)ws_size;
  const float* u   = (const float*)d_in[0];
  const float* Wdw = (const float*)d_in[1];
  const float* Wdb = (const float*)d_in[2];
  const float* WAw = (const float*)d_in[3];
  const float* WAb = (const float*)d_in[4];
  const float* WBw = (const float*)d_in[5];
  const float* WBb = (const float*)d_in[6];
  const float* Cw  = (const float*)d_in[7];
  const float* Dv  = (const float*)d_in[8];
  float* out = (float*)d_out;

  char* ws = (char*)d_ws;
  unsigned short* ub    = (unsigned short*)ws; ws += 16777216ull;   // u bf16
  unsigned short* WAb16 = (unsigned short*)ws; ws += 4194304ull;    // W_A bf16 (sigma-permuted rows)
  unsigned short* Wbd   = (unsigned short*)ws; ws += 131072ull;     // W_B|W_d bf16
  unsigned short* Aoff  = (unsigned short*)ws; ws += 134217728ull;  // A' bf16 [t][c*64+r], diag=0
  float* BuA   = (float*)ws; ws += 4194304ull;
  float* dA    = (float*)ws; ws += 4194304ull;
  float* hA    = (float*)ws; ws += 4194304ull;
  float* biasP = (float*)ws; ws += 16384ull;                        // permuted W_A bias

  prep_kernel<<<2048, 256, 0, stream>>>(u, WAw, WBw, Wdw, WAb, ub, WAb16, Wbd, biasP);
  gemm_kernel<1><<<dim3(128, 32), 256, 0, stream>>>(ub, WAb16, biasP, nullptr, Aoff, nullptr, nullptr, 128);
  gemm_kernel<2><<<dim3(128, 1), 256, 0, stream>>>(ub, Wbd, WBb, Wdb, nullptr, BuA, dA, 128);
  scan_kernel<<<dim3(32, 8), 256, 0, stream>>>(Aoff, BuA, dA, hA);
  out_kernel<<<dim3(512, 4), 256, 0, stream>>>(hA, Cw, Dv, u, out);
}